// Round 7
// baseline (175.194 us; speedup 1.0000x reference)
//
#include <hip/hip_runtime.h>
#include <math.h>

// Folded model (exact algebra, per-token):
//   h      = relu(x @ G1 + b11)                      [400 MACs]
//   g      = relu(h @ P1 + x @ P2 + f2)              [800 MACs]
//   logits = g @ M2 + h @ Q1 + x @ Q2 + f3           [180 MACs]
//   out    = softmax(logits)
// Logits weights stored TRANSPOSED and c-padded to 4 (M2T/Q1T/Q2T: [20][4]).

// d_ws layout (float offsets), 16B-aligned rows
#define OFF_G1   0      // [20][20] k-major
#define OFF_P1   400    // [20][20] m'-major
#define OFF_P2   800    // [20][20] k-major
#define OFF_M2T  1200   // [20][4]  M2T[m][c] = sum_p Wc[c][p]*W2_1[p][m], c3=0
#define OFF_Q1T  1280   // [20][4]  Q1T[k][c]
#define OFF_Q2T  1360   // [20][4]  Q2T[k][c]
#define OFF_B11  1440   // [20]
#define OFF_F2   1460   // [20]
#define OFF_F3   1480   // [3] + pad
#define NWTOT    1484

__global__ void prep_kernel(const float* __restrict__ Wv, const float* __restrict__ Wres,
                            const float* __restrict__ W1, const float* __restrict__ b1,
                            const float* __restrict__ W2, const float* __restrict__ b2,
                            const float* __restrict__ W3, const float* __restrict__ b3,
                            const float* __restrict__ Wc, const float* __restrict__ bc,
                            float* __restrict__ W) {
    __shared__ float G2[400];   // [i][m]
    __shared__ float M3[60];    // [i][c]
    __shared__ float e1[20];
    const int tid = threadIdx.x;
    for (int idx = tid; idx < 480; idx += 256) {
        if (idx < 400) {
            const int i = idx / 20, m = idx % 20;
            float s = 0.f;
            for (int j = 0; j < 20; ++j)
                s = fmaf(Wv[400 + j*20 + i] + Wres[400 + i*20 + j], W1[400 + m*20 + j], s);
            G2[idx] = s;
        } else if (idx < 460) {
            const int r = idx - 400, i = r / 3, c = r % 3;
            float s = 0.f;
            for (int p = 0; p < 20; ++p)
                s = fmaf(Wc[c*20 + p], W3[400 + p*20 + i], s);
            M3[r] = s;
        } else {
            const int j = idx - 460;
            e1[j] = b2[j] + b3[j];
        }
    }
    __syncthreads();
    for (int idx = tid; idx < NWTOT; idx += 256) {
        float s = 0.f;
        if (idx < 400) {                       // G1[k][m]
            const int k = idx / 20, m = idx % 20;
            for (int j = 0; j < 20; ++j)
                s = fmaf(Wv[j*20 + k] + Wres[k*20 + j], W1[m*20 + j], s);
        } else if (idx < 800) {                // P1[m'][m]
            const int r = idx - 400, mp = r / 20, m = r % 20;
            for (int i = 0; i < 20; ++i)
                s = fmaf(W2[i*20 + mp], G2[i*20 + m], s);
        } else if (idx < 1200) {               // P2[k][m]
            const int r = idx - 800, k = r / 20, m = r % 20;
            for (int i = 0; i < 20; ++i)
                s = fmaf(W3[i*20 + k], G2[i*20 + m], s);
        } else if (idx < 1280) {               // M2T[m][c]
            const int r = idx - 1200, m = r / 4, c = r % 4;
            if (c < 3)
                for (int p = 0; p < 20; ++p)
                    s = fmaf(Wc[c*20 + p], W2[400 + p*20 + m], s);
        } else if (idx < 1360) {               // Q1T[k][c]
            const int r = idx - 1280, k = r / 4, c = r % 4;
            if (c < 3)
                for (int i = 0; i < 20; ++i)
                    s = fmaf(W2[i*20 + k], M3[i*3 + c], s);
        } else if (idx < 1440) {               // Q2T[k][c]
            const int r = idx - 1360, k = r / 4, c = r % 4;
            if (c < 3)
                for (int i = 0; i < 20; ++i)
                    s = fmaf(W3[i*20 + k], M3[i*3 + c], s);
        } else if (idx < 1460) {               // b11
            s = b1[idx - 1440];
        } else if (idx < 1480) {               // f2
            const int m = idx - 1460;
            s = b1[20 + m];
            for (int i = 0; i < 20; ++i)
                s = fmaf(e1[i], G2[i*20 + m], s);
        } else {                               // f3 (+1 pad = 0)
            const int c = idx - 1480;
            if (c < 3) {
                s = bc[c];
                for (int p = 0; p < 20; ++p)
                    s = fmaf(Wc[c*20 + p], b2[20 + p] + b3[20 + p], s);
                for (int i = 0; i < 20; ++i)
                    s = fmaf(e1[i], M3[i*3 + c], s);
            }
        }
        W[idx] = s;
    }
}

// T=2, DUAL-PIPE weight delivery + packed-fp32 FMA.
// Evidence (7 runs): duration always ~133k cyc/CU = the single weight-pipe
// ceiling (LDS: 371 v4 x 12cyc x 32 waves = 136k, m134 constant; SMEM path
// lands the same); VALU busy is constant 89k cyc (1.9x the 46k true-FMA
// issue — parking/remat tax the scheduler always pays). Fix both walls:
//  - split weights: LDS carries G1+M2T (120 v4/thread -> 46k cyc),
//    SMEM carries P1/P2/Q1T/Q2T/biases (251 v4 -> ~42k cyc). Independent
//    pipes overlap.
//  - f2 (float2 ext-vector) accumulators + __builtin_elementwise_fma on
//    LDS-sourced rows -> v_pk_fma_f32 (2 MACs/instr), halving issue where
//    operand pairing is free (VGPR v4 rows). SMEM-sourced FMAs stay scalar
//    (SGPR operand is free in VOP3; pk there would cost movs).
typedef float f2  __attribute__((ext_vector_type(2)));
typedef float v4f __attribute__((ext_vector_type(4)));
typedef const __attribute__((address_space(4))) v4f  c4f_t;
typedef const __attribute__((address_space(4))) float cfl_t;

__global__ __launch_bounds__(256, 3) void fwd_kernel(const float* __restrict__ X,
                                                     const float* __restrict__ Wg,
                                                     float* __restrict__ out, int npair) {
    __shared__ float Ws[480];              // [0..400) = G1, [400..480) = M2T
    for (int i = threadIdx.x; i < 480; i += 256)
        Ws[i] = (i < 400) ? Wg[OFF_G1 + i] : Wg[OFF_M2T + (i - 400)];
    __syncthreads();
    const v4f* L4 = reinterpret_cast<const v4f*>(Ws);

    c4f_t* W4 = (c4f_t*)(unsigned long long)Wg;
    cfl_t* Wf = (cfl_t*)(unsigned long long)Wg;

    const int pair = blockIdx.x * blockDim.x + threadIdx.x;
    if (pair >= npair) return;

    // load 2 tokens (40 consecutive floats) up-front
    float xa[20], xb[20];
    const float4* xp = reinterpret_cast<const float4*>(X + (size_t)pair * 40);
    #pragma unroll
    for (int q = 0; q < 5; ++q) {
        const float4 v = xp[q];
        xa[4*q+0] = v.x; xa[4*q+1] = v.y; xa[4*q+2] = v.z; xa[4*q+3] = v.w;
    }
    #pragma unroll
    for (int q = 0; q < 5; ++q) {
        const float4 v = xp[5 + q];
        xb[4*q+0] = v.x; xb[4*q+1] = v.y; xb[4*q+2] = v.z; xb[4*q+3] = v.w;
    }

    f2 h2[2][10], g2[2][10], la2[2][2];

    // init: h = b11, g = f2, la = f3 (SMEM)
    #pragma unroll
    for (int q = 0; q < 5; ++q) {
        const v4f b = W4[OFF_B11/4 + q];
        const v4f f = W4[OFF_F2/4 + q];
        #pragma unroll
        for (int j = 0; j < 2; ++j) {
            f2 blo = {b.x, b.y}; f2 bhi = {b.z, b.w};
            f2 flo = {f.x, f.y}; f2 fhi = {f.z, f.w};
            h2[j][2*q+0] = blo; h2[j][2*q+1] = bhi;
            g2[j][2*q+0] = flo; g2[j][2*q+1] = fhi;
        }
    }
    {
        const float f30 = Wf[OFF_F3+0], f31 = Wf[OFF_F3+1], f32v = Wf[OFF_F3+2];
        #pragma unroll
        for (int j = 0; j < 2; ++j) {
            f2 lo = {f30, f31}; f2 hi = {f32v, 0.f};
            la2[j][0] = lo; la2[j][1] = hi;
        }
    }

    // ---- loop1: h += x@G1 (LDS, packed) ; g += x@P2 (SMEM, scalar) ;
    //             la += x@Q2T (SMEM, scalar) ----
    #pragma unroll
    for (int k = 0; k < 20; ++k) {
        const float x0 = xa[k], x1 = xb[k];
        const f2 x0p = {x0, x0};
        const f2 x1p = {x1, x1};
        #pragma unroll
        for (int r = 0; r < 5; ++r) {
            const v4f w = L4[k*5 + r];
            const f2 wlo = {w.x, w.y};
            const f2 whi = {w.z, w.w};
            h2[0][2*r+0] = __builtin_elementwise_fma(x0p, wlo, h2[0][2*r+0]);
            h2[0][2*r+1] = __builtin_elementwise_fma(x0p, whi, h2[0][2*r+1]);
            h2[1][2*r+0] = __builtin_elementwise_fma(x1p, wlo, h2[1][2*r+0]);
            h2[1][2*r+1] = __builtin_elementwise_fma(x1p, whi, h2[1][2*r+1]);
        }
        #pragma unroll
        for (int r = 0; r < 5; ++r) {
            const v4f w = W4[OFF_P2/4 + k*5 + r];
            g2[0][2*r+0].x = fmaf(x0, w.x, g2[0][2*r+0].x);
            g2[0][2*r+0].y = fmaf(x0, w.y, g2[0][2*r+0].y);
            g2[0][2*r+1].x = fmaf(x0, w.z, g2[0][2*r+1].x);
            g2[0][2*r+1].y = fmaf(x0, w.w, g2[0][2*r+1].y);
            g2[1][2*r+0].x = fmaf(x1, w.x, g2[1][2*r+0].x);
            g2[1][2*r+0].y = fmaf(x1, w.y, g2[1][2*r+0].y);
            g2[1][2*r+1].x = fmaf(x1, w.z, g2[1][2*r+1].x);
            g2[1][2*r+1].y = fmaf(x1, w.w, g2[1][2*r+1].y);
        }
        const v4f wq = W4[OFF_Q2T/4 + k];
        la2[0][0].x = fmaf(x0, wq.x, la2[0][0].x);
        la2[0][0].y = fmaf(x0, wq.y, la2[0][0].y);
        la2[0][1].x = fmaf(x0, wq.z, la2[0][1].x);
        la2[1][0].x = fmaf(x1, wq.x, la2[1][0].x);
        la2[1][0].y = fmaf(x1, wq.y, la2[1][0].y);
        la2[1][1].x = fmaf(x1, wq.z, la2[1][1].x);
    }

    // relu h (packed max)
    {
        const f2 z2 = {0.f, 0.f};
        #pragma unroll
        for (int j = 0; j < 2; ++j)
            #pragma unroll
            for (int p = 0; p < 10; ++p)
                h2[j][p] = __builtin_elementwise_max(h2[j][p], z2);
    }

    // ---- loop2: g += h@P1 (SMEM, scalar) ; la += h@Q1T (SMEM, scalar) ----
    #pragma unroll
    for (int k = 0; k < 20; ++k) {
        const float h0 = (k & 1) ? h2[0][k>>1].y : h2[0][k>>1].x;
        const float h1 = (k & 1) ? h2[1][k>>1].y : h2[1][k>>1].x;
        const v4f wq = W4[OFF_Q1T/4 + k];
        la2[0][0].x = fmaf(h0, wq.x, la2[0][0].x);
        la2[0][0].y = fmaf(h0, wq.y, la2[0][0].y);
        la2[0][1].x = fmaf(h0, wq.z, la2[0][1].x);
        la2[1][0].x = fmaf(h1, wq.x, la2[1][0].x);
        la2[1][0].y = fmaf(h1, wq.y, la2[1][0].y);
        la2[1][1].x = fmaf(h1, wq.z, la2[1][1].x);
        #pragma unroll
        for (int r = 0; r < 5; ++r) {
            const v4f w = W4[OFF_P1/4 + k*5 + r];
            g2[0][2*r+0].x = fmaf(h0, w.x, g2[0][2*r+0].x);
            g2[0][2*r+0].y = fmaf(h0, w.y, g2[0][2*r+0].y);
            g2[0][2*r+1].x = fmaf(h0, w.z, g2[0][2*r+1].x);
            g2[0][2*r+1].y = fmaf(h0, w.w, g2[0][2*r+1].y);
            g2[1][2*r+0].x = fmaf(h1, w.x, g2[1][2*r+0].x);
            g2[1][2*r+0].y = fmaf(h1, w.y, g2[1][2*r+0].y);
            g2[1][2*r+1].x = fmaf(h1, w.z, g2[1][2*r+1].x);
            g2[1][2*r+1].y = fmaf(h1, w.w, g2[1][2*r+1].y);
        }
    }

    // relu g (packed max)
    {
        const f2 z2 = {0.f, 0.f};
        #pragma unroll
        for (int j = 0; j < 2; ++j)
            #pragma unroll
            for (int p = 0; p < 10; ++p)
                g2[j][p] = __builtin_elementwise_max(g2[j][p], z2);
    }

    // ---- loop3: la += g@M2T (LDS, packed; c-padded to 4, pad col = 0) ----
    #pragma unroll
    for (int k = 0; k < 20; ++k) {
        const float g0 = (k & 1) ? g2[0][k>>1].y : g2[0][k>>1].x;
        const float g1 = (k & 1) ? g2[1][k>>1].y : g2[1][k>>1].x;
        const v4f w = L4[100 + k];
        const f2 wlo = {w.x, w.y};
        const f2 whi = {w.z, w.w};
        const f2 g0p = {g0, g0};
        const f2 g1p = {g1, g1};
        la2[0][0] = __builtin_elementwise_fma(g0p, wlo, la2[0][0]);
        la2[0][1] = __builtin_elementwise_fma(g0p, whi, la2[0][1]);
        la2[1][0] = __builtin_elementwise_fma(g1p, wlo, la2[1][0]);
        la2[1][1] = __builtin_elementwise_fma(g1p, whi, la2[1][1]);
    }

    // softmax per token + store (2 tokens x 3 probs = 6 floats, 8B-aligned)
    float p[6];
    #pragma unroll
    for (int j = 0; j < 2; ++j) {
        const float l0 = la2[j][0].x, l1 = la2[j][0].y, l2 = la2[j][1].x;
        const float m = fmaxf(fmaxf(l0, l1), l2);
        const float e0 = __expf(l0 - m);
        const float e1 = __expf(l1 - m);
        const float e2 = __expf(l2 - m);
        const float r = 1.f / (e0 + e1 + e2);
        p[3*j+0] = e0 * r; p[3*j+1] = e1 * r; p[3*j+2] = e2 * r;
    }
    float2* o2 = reinterpret_cast<float2*>(out + (size_t)pair * 6);
    o2[0] = make_float2(p[0], p[1]);
    o2[1] = make_float2(p[2], p[3]);
    o2[2] = make_float2(p[4], p[5]);
}

extern "C" void kernel_launch(void* const* d_in, const int* in_sizes, int n_in,
                              void* d_out, int out_size, void* d_ws, size_t ws_size,
                              hipStream_t stream) {
    const float* X    = (const float*)d_in[0];
    // d_in[1]=Wq, d_in[2]=Wk: dead (softmax over singleton axis == 1)
    const float* Wv   = (const float*)d_in[3];
    const float* Wres = (const float*)d_in[4];
    const float* W1   = (const float*)d_in[5];
    const float* b1   = (const float*)d_in[6];
    const float* W2   = (const float*)d_in[7];
    const float* b2   = (const float*)d_in[8];
    const float* W3   = (const float*)d_in[9];
    const float* b3   = (const float*)d_in[10];
    const float* Wc   = (const float*)d_in[11];
    const float* bc   = (const float*)d_in[12];
    float* out = (float*)d_out;
    float* W   = (float*)d_ws;

    const int S = in_sizes[0] / 20;
    const int npair = S / 2;   // S = 1048576 divides evenly

    prep_kernel<<<1, 256, 0, stream>>>(Wv, Wres, W1, b1, W2, b2, W3, b3, Wc, bc, W);

    const int block = 256;
    const int grid = (npair + block - 1) / block;
    fwd_kernel<<<grid, block, 0, stream>>>(X, W, out, npair);
}